// Round 3
// baseline (376.223 us; speedup 1.0000x reference)
//
#include <hip/hip_runtime.h>
#include <stdint.h>

// ---------------------------------------------------------------------------
// SelfAttentionBlock (BigGAN-style), B=16 C=256 H=W=64.
//   theta = w_theta@x            [B,32,4096]   (fp32)
//   phi   = pool2x2(w_phi@x)     [B,32,1024]   (fp32)
//   g     = pool2x2(w_g@x)       [B,128,1024]  (fp32)
//   beta  = softmax(theta^T phi) [B,4096,1024] (bf16 in ws)
//   W_og  = w_o @ g              [B,256,1024]  (bf16 in ws)
//   out   = gamma * (W_og @ beta^T) + x        (fp32, bf16-MFMA K4)
//
// Numeric split (deliberate): QK^T + softmax in fp32 (sharp softmax amplifies
// score error ~10x); only the error-averaging PV operands (beta, W_og) are
// bf16 (~0.3-0.5% on attention term; residual x exact).
// ---------------------------------------------------------------------------

#define B_  16
#define C_  256
#define HW_ 4096
#define C8_ 32
#define C2_ 128
#define P_  1024

// ws layout in float units
#define WS_THETA 0u
#define WS_PHI   2097152u          // + 16*32*4096        (theta fp32)
#define WS_G     2621440u          // + 16*32*1024        (phi fp32)
#define WS_WOG   4718592u          // + 16*128*1024       (g fp32)
#define WS_BETA  6815744u          // + 16*256*1024/2     (wog bf16)
// beta bf16: 16*4096*1024 ushort = 33,554,432 float-units
// total = 40,370,176 floats = 161.5 MB

// ---- bf16 helpers (RNE) ---------------------------------------------------
__device__ inline unsigned short f2bf(float f) {
    unsigned int u = __builtin_bit_cast(unsigned int, f);
    u = (u + 0x7fffu + ((u >> 16) & 1u)) >> 16;
    return (unsigned short)u;
}
__device__ inline void beta_store4(unsigned short* p, float a, float b, float c, float d) {
    ushort4 v; v.x = f2bf(a); v.y = f2bf(b); v.z = f2bf(c); v.w = f2bf(d);
    *(ushort4*)p = v;
}

typedef __attribute__((ext_vector_type(8))) short bf16x8;
typedef __attribute__((ext_vector_type(4))) float f32x4;

// global -> LDS direct staging, 16B per lane, linear LDS dest (lane-ordered)
#define GLOAD_LDS(gsrc, ldst) __builtin_amdgcn_global_load_lds( \
    (__attribute__((address_space(1))) void*)(uintptr_t)(const void*)(gsrc), \
    (__attribute__((address_space(3))) void*)(ldst), 16, 0, 0)

// ---------------------------------------------------------------------------
// K1: projections + fused 2x2 maxpool.  grid (32 ht, 3 ogrp, 16 b), block 256.
// ogrp 0: rows 0..31 theta (no pool), rows 32..63 phi (pool)
// ogrp 1: g rows 0..63 (pool); ogrp 2: g rows 64..127 (pool)
// Tile: [64 o] x [128 s]  (s = 2 image rows, contiguous hw)
// ---------------------------------------------------------------------------
__global__ __launch_bounds__(256) void k1_proj(
    const float* __restrict__ x, const float* __restrict__ w_theta,
    const float* __restrict__ w_phi, const float* __restrict__ w_g,
    float* __restrict__ theta_o, float* __restrict__ phi_o, float* __restrict__ g_o)
{
    const int ht = blockIdx.x, ogrp = blockIdx.y, b = blockIdx.z;
    const int tid = threadIdx.x;
    __shared__ float xs[64][128];   // c-chunk x s (32KB); reused as out stage
    __shared__ float wl[64][64];    // o x c-chunk (16KB)

    float acc[8][4] = {};
    const int o_thr = tid >> 5;     // 0..7  (o = o_thr + 8i)
    const int s_thr = tid & 31;     // 0..31 (s = s_thr*4 + j)
    const float* xb = x + ((size_t)b * C_) * HW_ + (size_t)ht * 128;

    const int wo_row = tid >> 2;    // 0..63
    const float* wsrc;
    if (ogrp == 0) wsrc = (wo_row < 32) ? (w_theta + wo_row * 256)
                                        : (w_phi + (wo_row - 32) * 256);
    else if (ogrp == 1) wsrc = w_g + wo_row * 256;
    else wsrc = w_g + (wo_row + 64) * 256;

    for (int c0 = 0; c0 < 256; c0 += 64) {
        __syncthreads();
        { // x chunk [64 c][128 s]
            const int c = tid >> 2, sseg = (tid & 3) * 32;
            const float* src = xb + (size_t)(c0 + c) * HW_ + sseg;
            #pragma unroll
            for (int u = 0; u < 8; ++u)
                *(float4*)&xs[c][sseg + u * 4] = *(const float4*)&src[u * 4];
        }
        { // w chunk [64 o][64 c]
            const int cseg = (tid & 3) * 16;
            #pragma unroll
            for (int u = 0; u < 4; ++u)
                *(float4*)&wl[wo_row][cseg + u * 4] =
                    *(const float4*)&wsrc[c0 + cseg + u * 4];
        }
        __syncthreads();
        #pragma unroll 4
        for (int c = 0; c < 64; ++c) {
            float4 xv = *(const float4*)&xs[c][s_thr * 4];
            float wv[8];
            #pragma unroll
            for (int i = 0; i < 8; ++i) wv[i] = wl[o_thr + 8 * i][c];
            #pragma unroll
            for (int i = 0; i < 8; ++i) {
                acc[i][0] += wv[i] * xv.x;
                acc[i][1] += wv[i] * xv.y;
                acc[i][2] += wv[i] * xv.z;
                acc[i][3] += wv[i] * xv.w;
            }
        }
    }
    __syncthreads();
    #pragma unroll
    for (int i = 0; i < 8; ++i)
        #pragma unroll
        for (int j = 0; j < 4; ++j)
            xs[o_thr + 8 * i][s_thr * 4 + j] = acc[i][j];
    __syncthreads();

    if (ogrp == 0) {
        { // theta rows 0..31 direct
            const int o = tid >> 3, k = (tid & 7) * 16;
            float* dst = theta_o + ((size_t)b * C8_ + o) * HW_ + (size_t)ht * 128 + k;
            #pragma unroll
            for (int u = 0; u < 4; ++u)
                *(float4*)&dst[u * 4] = *(float4*)&xs[o][k + u * 4];
        }
        { // phi rows 32..63 pooled -> [32 o][32 w2]
            const int o2 = tid >> 3, wq = (tid & 7) * 4;
            float* dst = phi_o + ((size_t)b * C8_ + o2) * P_ + (size_t)ht * 32 + wq;
            #pragma unroll
            for (int u = 0; u < 4; ++u) {
                int w2 = wq + u;
                dst[u] = fmaxf(fmaxf(xs[32 + o2][2 * w2], xs[32 + o2][2 * w2 + 1]),
                               fmaxf(xs[32 + o2][64 + 2 * w2], xs[32 + o2][64 + 2 * w2 + 1]));
            }
        }
    } else {
        const int base = (ogrp - 1) * 64;
        const int o = tid >> 2, wq = (tid & 3) * 8;
        float* dst = g_o + ((size_t)b * C2_ + base + o) * P_ + (size_t)ht * 32 + wq;
        #pragma unroll
        for (int u = 0; u < 8; ++u) {
            int w2 = wq + u;
            dst[u] = fmaxf(fmaxf(xs[o][2 * w2], xs[o][2 * w2 + 1]),
                           fmaxf(xs[o][64 + 2 * w2], xs[o][64 + 2 * w2 + 1]));
        }
    }
}

// ---------------------------------------------------------------------------
// K2: W_og[b] = w_o[256,128] @ g[b][128,1024]  -> bf16 output.
// grid (16 p-tiles, 4 co-tiles, 16 b), block 256 (4 waves).
// ---------------------------------------------------------------------------
__global__ __launch_bounds__(256) void k2_wog(
    const float* __restrict__ w_o, const float* __restrict__ g,
    unsigned short* __restrict__ wog)
{
    const int p0 = blockIdx.x * 64, cb = blockIdx.y, b = blockIdx.z;
    const int tid = threadIdx.x, wv = tid >> 6, lane = tid & 63;
    __shared__ float wls[64][128];  // [co][c2]  32KB
    __shared__ float gls[128][64];  // [c2][p]   32KB

    {
        const int o = tid >> 2, q = (tid & 3) * 32;
        const float* src = w_o + (size_t)(cb * 64 + o) * 128 + q;
        #pragma unroll
        for (int u = 0; u < 8; ++u)
            *(float4*)&wls[o][q + u * 4] = *(const float4*)&src[u * 4];
        const int c2 = tid >> 1, h = (tid & 1) * 32;
        const float* gsrc = g + ((size_t)b * C2_ + c2) * P_ + p0 + h;
        #pragma unroll
        for (int u = 0; u < 8; ++u)
            *(float4*)&gls[c2][h + u * 4] = *(const float4*)&gsrc[u * 4];
    }
    __syncthreads();

    float acc[16] = {};
    for (int k4 = 0; k4 < 32; ++k4) {
        float gk[4];
        #pragma unroll
        for (int kk = 0; kk < 4; ++kk) gk[kk] = gls[k4 * 4 + kk][lane];
        #pragma unroll
        for (int i = 0; i < 16; ++i) {
            float4 w4 = *(const float4*)&wls[wv * 16 + i][k4 * 4];
            acc[i] += w4.x * gk[0] + w4.y * gk[1] + w4.z * gk[2] + w4.w * gk[3];
        }
    }
    #pragma unroll
    for (int i = 0; i < 16; ++i)
        wog[((size_t)b * C_ + cb * 64 + wv * 16 + i) * P_ + p0 + lane] = f2bf(acc[i]);
}

// ---------------------------------------------------------------------------
// K3: scores + softmax -> beta (bf16).  scores[t,p] = sum_c theta[c,t]*phi[c,p]
// grid (256 t-tiles of 16, 16 b), block 256 (4 waves).  fp32 throughout;
// bf16 rounding only at the final normalized-beta store.
// ---------------------------------------------------------------------------
__global__ __launch_bounds__(256) void k3_softmax(
    const float* __restrict__ theta, const float* __restrict__ phi,
    unsigned short* __restrict__ beta)
{
    const int t0 = blockIdx.x * 16, b = blockIdx.y;
    const int tid = threadIdx.x, wv = tid >> 6, lane = tid & 63;
    __shared__ float th[32][16];    // [c][t]   2KB
    __shared__ float ph[32][256];   // [c][p]   32KB

    if (tid < 128) {
        const int c = tid >> 2, tq = (tid & 3) * 4;
        *(float4*)&th[c][tq] =
            *(const float4*)&theta[((size_t)b * C8_ + c) * HW_ + t0 + tq];
    }

    float s[4][16] = {};
    #pragma unroll
    for (int ch = 0; ch < 4; ++ch) {
        __syncthreads();
        {
            const int c = tid >> 3, p8 = (tid & 7) * 4;
            const float* src = phi + ((size_t)b * C8_ + c) * P_ + ch * 256;
            #pragma unroll
            for (int u = 0; u < 8; ++u)
                *(float4*)&ph[c][p8 + u * 32] = *(const float4*)&src[p8 + u * 32];
        }
        __syncthreads();
        for (int c = 0; c < 32; ++c) {
            float4 pv = *(const float4*)&ph[c][lane * 4];
            #pragma unroll
            for (int r = 0; r < 4; ++r) {
                float tv = th[c][wv * 4 + r];
                s[r][ch * 4 + 0] += tv * pv.x;
                s[r][ch * 4 + 1] += tv * pv.y;
                s[r][ch * 4 + 2] += tv * pv.z;
                s[r][ch * 4 + 3] += tv * pv.w;
            }
        }
    }

    #pragma unroll
    for (int r = 0; r < 4; ++r) {
        float m = s[r][0];
        #pragma unroll
        for (int q = 1; q < 16; ++q) m = fmaxf(m, s[r][q]);
        #pragma unroll
        for (int off = 32; off > 0; off >>= 1) m = fmaxf(m, __shfl_xor(m, off));
        float sum = 0.f;
        #pragma unroll
        for (int q = 0; q < 16; ++q) { s[r][q] = __expf(s[r][q] - m); sum += s[r][q]; }
        #pragma unroll
        for (int off = 32; off > 0; off >>= 1) sum += __shfl_xor(sum, off);
        const float rl = 1.0f / sum;
        unsigned short* dst = beta + ((size_t)b * HW_ + t0 + wv * 4 + r) * P_;
        #pragma unroll
        for (int ch = 0; ch < 4; ++ch)
            beta_store4(&dst[ch * 256 + lane * 4],
                        s[r][ch * 4 + 0] * rl, s[r][ch * 4 + 1] * rl,
                        s[r][ch * 4 + 2] * rl, s[r][ch * 4 + 3] * rl);
    }
}

// ---------------------------------------------------------------------------
// K4: out[b,co,t] = gamma * sum_p Wog[b,co,p]*beta[b,t,p] + x[b,co,t]
// bf16 MFMA 16x16x32, m97 structure: 128x128 tile, BK=64, 4 waves (2x2),
// 4x4 frags/wave, global_load_lds width-16 linear staging.
// Both operands K-major -> contiguous 16B/lane fragment reads.
// grid (32 t-tiles, 2 co-tiles, 16 b), block 256.
// ---------------------------------------------------------------------------
__global__ __launch_bounds__(256) void k4_mfma(
    const unsigned short* __restrict__ wog, const unsigned short* __restrict__ beta,
    const float* __restrict__ x, const float* __restrict__ gamma_p,
    float* __restrict__ out)
{
    const int t0 = blockIdx.x * 128, c0 = blockIdx.y * 128, b = blockIdx.z;
    const int tid = threadIdx.x, wv = tid >> 6, lane = tid & 63;
    const int wm = wv >> 1, wn = wv & 1;        // wave 2x2 grid
    const int lr = lane & 15, lk = lane >> 4;   // frag row/col, k-block
    __shared__ unsigned short As[128 * 64];     // [co-rel][p-rel], 16KB
    __shared__ unsigned short Bs[128 * 64];     // [t-rel][p-rel],  16KB

    f32x4 acc[4][4] = {};
    const unsigned short* wog_b  = wog  + ((size_t)b * C_  + c0) * P_;
    const unsigned short* beta_b = beta + ((size_t)b * HW_ + t0) * P_;

    for (int p0 = 0; p0 < 1024; p0 += 64) {
        __syncthreads();
        #pragma unroll
        for (int ch = 0; ch < 4; ++ch) {
            const int i16 = ch * 256 + tid;        // 16B unit index 0..1023
            const int row = i16 >> 3, cb8 = i16 & 7;
            GLOAD_LDS(wog_b  + (size_t)row * P_ + p0 + cb8 * 8, &As[i16 * 8]);
            GLOAD_LDS(beta_b + (size_t)row * P_ + p0 + cb8 * 8, &Bs[i16 * 8]);
        }
        __syncthreads();

        #pragma unroll
        for (int ks = 0; ks < 2; ++ks) {
            bf16x8 af[4], bfr[4];
            #pragma unroll
            for (int mf = 0; mf < 4; ++mf)
                af[mf] = *(const bf16x8*)&As[(wm * 64 + mf * 16 + lr) * 64 + ks * 32 + lk * 8];
            #pragma unroll
            for (int nf = 0; nf < 4; ++nf)
                bfr[nf] = *(const bf16x8*)&Bs[(wn * 64 + nf * 16 + lr) * 64 + ks * 32 + lk * 8];
            #pragma unroll
            for (int mf = 0; mf < 4; ++mf)
                #pragma unroll
                for (int nf = 0; nf < 4; ++nf)
                    acc[mf][nf] = __builtin_amdgcn_mfma_f32_16x16x32_bf16(
                        af[mf], bfr[nf], acc[mf][nf], 0, 0, 0);
        }
    }

    // C/D layout (m89/m91): col = lane&15 -> t, row = (lane>>4)*4 + reg -> co
    const float gm = gamma_p[0];
    #pragma unroll
    for (int mf = 0; mf < 4; ++mf) {
        #pragma unroll
        for (int r = 0; r < 4; ++r) {
            const int co = c0 + wm * 64 + mf * 16 + lk * 4 + r;
            const size_t rowoff = ((size_t)b * C_ + co) * HW_;
            #pragma unroll
            for (int nf = 0; nf < 4; ++nf) {
                const int t = t0 + wn * 64 + nf * 16 + lr;
                out[rowoff + t] = gm * acc[mf][nf][r] + x[rowoff + t];
            }
        }
    }
}

// ---------------------------------------------------------------------------
extern "C" void kernel_launch(void* const* d_in, const int* in_sizes, int n_in,
                              void* d_out, int out_size, void* d_ws, size_t ws_size,
                              hipStream_t stream)
{
    const float* x       = (const float*)d_in[0];
    const float* w_theta = (const float*)d_in[1];
    const float* w_phi   = (const float*)d_in[2];
    const float* w_g     = (const float*)d_in[3];
    const float* w_o     = (const float*)d_in[4];
    const float* gamma   = (const float*)d_in[5];
    float* out = (float*)d_out;
    float* ws  = (float*)d_ws;

    float* theta          = ws + WS_THETA;
    float* phi            = ws + WS_PHI;
    float* g              = ws + WS_G;
    unsigned short* wog   = (unsigned short*)(ws + WS_WOG);
    unsigned short* beta  = (unsigned short*)(ws + WS_BETA);

    k1_proj<<<dim3(32, 3, 16), 256, 0, stream>>>(x, w_theta, w_phi, w_g,
                                                 theta, phi, g);
    k2_wog<<<dim3(16, 4, 16), 256, 0, stream>>>(w_o, g, wog);
    k3_softmax<<<dim3(256, 16), 256, 0, stream>>>(theta, phi, beta);
    k4_mfma<<<dim3(32, 2, 16), 256, 0, stream>>>(wog, beta, x, gamma, out);
}

// Round 6
// 331.979 us; speedup vs baseline: 1.1333x; 1.1333x over previous
//
#include <hip/hip_runtime.h>
#include <stdint.h>

// ---------------------------------------------------------------------------
// SelfAttentionBlock (BigGAN-style), B=16 C=256 H=W=64.
//   theta = w_theta@x            [B,32,4096]   (fp32 via split-bf16 MFMA)
//   phi   = pool2x2(w_phi@x)     [B,32,1024]   (fp32 via split-bf16 MFMA)
//   g     = pool2x2(w_g@x)       [B,128,1024]  (fp32 via split-bf16 MFMA)
//   beta  = softmax(theta^T phi) [B,4096,1024] (bf16 in ws)
//   W_og  = w_o @ g              [B,256,1024]  (bf16 in ws)
//   out   = gamma * (W_og @ beta^T) + x        (fp32, bf16-MFMA K4)
//
// k1 numeric scheme: 3-term split-bf16 (f = hi + lo; acc += Ah*Bh + Ah*Bl
// + Al*Bh) => ~1.5e-5 rel err, fp32-class. Softmax fp32. Only PV operands
// (beta, W_og) are bf16. No tr16 / no inline asm — only primitives verified
// in the round-3 pass (k4 fragment layouts, round-3 staging patterns).
// ---------------------------------------------------------------------------

#define B_  16
#define C_  256
#define HW_ 4096
#define C8_ 32
#define C2_ 128
#define P_  1024

// ws layout in float units
#define WS_THETA 0u
#define WS_PHI   2097152u          // + 16*32*4096        (theta fp32)
#define WS_G     2621440u          // + 16*32*1024        (phi fp32)
#define WS_WOG   4718592u          // + 16*128*1024       (g fp32)
#define WS_BETA  6815744u          // + 16*256*1024/2     (wog bf16)

// ---- bf16 helpers ---------------------------------------------------------
__device__ inline unsigned short f2bf(float f) {          // RNE
    unsigned int u = __builtin_bit_cast(unsigned int, f);
    u = (u + 0x7fffu + ((u >> 16) & 1u)) >> 16;
    return (unsigned short)u;
}
__device__ inline void beta_store4(unsigned short* p, float a, float b, float c, float d) {
    ushort4 v; v.x = f2bf(a); v.y = f2bf(b); v.z = f2bf(c); v.w = f2bf(d);
    *(ushort4*)p = v;
}
// truncation split: f = hi + lo + O(2^-16 |f|)
__device__ inline void splitbf(float f, unsigned short& h, unsigned short& l) {
    unsigned u = __builtin_bit_cast(unsigned, f);
    h = (unsigned short)(u >> 16);
    float lof = f - __builtin_bit_cast(float, u & 0xffff0000u);
    l = (unsigned short)(__builtin_bit_cast(unsigned, lof) >> 16);
}

typedef __attribute__((ext_vector_type(8))) short bf16x8;
typedef __attribute__((ext_vector_type(8))) unsigned short u16x8;
typedef __attribute__((ext_vector_type(4))) float f32x4;

// global -> LDS direct staging, 16B per lane, linear LDS dest (lane-ordered)
#define GLOAD_LDS(gsrc, ldst) __builtin_amdgcn_global_load_lds( \
    (__attribute__((address_space(1))) void*)(uintptr_t)(const void*)(gsrc), \
    (__attribute__((address_space(3))) void*)(ldst), 16, 0, 0)

// ---------------------------------------------------------------------------
// K1: projections + fused 2x2 maxpool via split-bf16 MFMA (16x16x32).
// grid (32 ht, 3 ogrp, 16 b), block 256 = 4 waves.
// Output tile [64 o][128 s]; wave wv owns s-range [wv*32, wv*32+32) (nf=2),
// all 64 o (mf=4). K=256 in 4 chunks of 64 (ks=2 per chunk).
// LDS: xs fp32 [64 c][128 s] (32KB, round-3 staging; reused as out stage);
//      WH/WL split-bf16 [64 o][72 c] (pad->36-word row stride: bank-balanced
//      for u16x8 writes and b128 fragment reads). 50KB total -> 3 blocks/CU.
// A-frags: ds_read_b128 from WH/WL (k4-proven layout: row=lr, k=ks*32+lk*8).
// B-frags: 8x fp32 column reads from xs (4-way conflict, 1.58x - accepted),
//          split in-register. 3 MFMA per (mf,nf) pair.
// C/D: col=lane&15 -> s, row=(lane>>4)*4+reg -> o (k4-verified mapping).
// ---------------------------------------------------------------------------
__global__ __launch_bounds__(256, 3) void k1_proj(
    const float* __restrict__ x, const float* __restrict__ w_theta,
    const float* __restrict__ w_phi, const float* __restrict__ w_g,
    float* __restrict__ theta_o, float* __restrict__ phi_o, float* __restrict__ g_o)
{
    const int ht = blockIdx.x, ogrp = blockIdx.y, b = blockIdx.z;
    const int tid = threadIdx.x;
    const int lane = tid & 63, wv = tid >> 6;
    const int lr = lane & 15, lk = lane >> 4;

    __shared__ float xs[64 * 128];            // fp32 [c][s]; later [o][s] stage
    __shared__ unsigned short WHs[64 * 72];   // [o][c] hi (pad 72)
    __shared__ unsigned short WLs[64 * 72];   // [o][c] lo

    const float* xb = x + ((size_t)b * C_) * HW_ + (size_t)ht * 128;
    const int c_ld = tid >> 2;            // x stage: c row 0..63
    const int sseg = (tid & 3) * 32;      // x stage: s segment
    const int o_ld = tid >> 2;            // W stage: o row 0..63
    const int cseg = (tid & 3) * 16;      // W stage: c segment

    const float* wsrc;
    if (ogrp == 0) wsrc = (o_ld < 32) ? (w_theta + o_ld * 256)
                                      : (w_phi + (o_ld - 32) * 256);
    else if (ogrp == 1) wsrc = w_g + o_ld * 256;
    else wsrc = w_g + (o_ld + 64) * 256;

    f32x4 acc[4][2] = {};

    for (int kc = 0; kc < 4; ++kc) {
        const int c0 = kc * 64;
        __syncthreads();
        { // x chunk [64 c][128 s] -> fp32 LDS (round-3 verified pattern)
            const float* src = xb + (size_t)(c0 + c_ld) * HW_ + sseg;
            #pragma unroll
            for (int u = 0; u < 8; ++u)
                *(float4*)&xs[c_ld * 128 + sseg + u * 4] = *(const float4*)&src[u * 4];
        }
        { // W chunk [64 o][64 c] -> split-bf16 LDS
            #pragma unroll
            for (int h = 0; h < 2; ++h) {
                u16x8 hi, lo;
                #pragma unroll
                for (int e = 0; e < 8; ++e) {
                    unsigned short hh, ll;
                    splitbf(wsrc[c0 + cseg + h * 8 + e], hh, ll);
                    hi[e] = hh; lo[e] = ll;
                }
                *(u16x8*)&WHs[o_ld * 72 + cseg + h * 8] = hi;
                *(u16x8*)&WLs[o_ld * 72 + cseg + h * 8] = lo;
            }
        }
        __syncthreads();

        #pragma unroll
        for (int ks = 0; ks < 2; ++ks) {
            bf16x8 Ah[4], Al[4];
            #pragma unroll
            for (int mf = 0; mf < 4; ++mf) {
                Ah[mf] = *(const bf16x8*)&WHs[(mf * 16 + lr) * 72 + ks * 32 + lk * 8];
                Al[mf] = *(const bf16x8*)&WLs[(mf * 16 + lr) * 72 + ks * 32 + lk * 8];
            }
            #pragma unroll
            for (int nf = 0; nf < 2; ++nf) {
                const int s = wv * 32 + nf * 16 + lr;
                u16x8 hi, lo;
                #pragma unroll
                for (int e = 0; e < 8; ++e) {
                    unsigned short hh, ll;
                    splitbf(xs[(ks * 32 + lk * 8 + e) * 128 + s], hh, ll);
                    hi[e] = hh; lo[e] = ll;
                }
                const bf16x8 Bh = __builtin_bit_cast(bf16x8, hi);
                const bf16x8 Bl = __builtin_bit_cast(bf16x8, lo);
                #pragma unroll
                for (int mf = 0; mf < 4; ++mf) {
                    acc[mf][nf] = __builtin_amdgcn_mfma_f32_16x16x32_bf16(
                        Ah[mf], Bh, acc[mf][nf], 0, 0, 0);
                    acc[mf][nf] = __builtin_amdgcn_mfma_f32_16x16x32_bf16(
                        Ah[mf], Bl, acc[mf][nf], 0, 0, 0);
                    acc[mf][nf] = __builtin_amdgcn_mfma_f32_16x16x32_bf16(
                        Al[mf], Bh, acc[mf][nf], 0, 0, 0);
                }
            }
        }
    }

    __syncthreads();   // all fragment reads done -> xs reusable as [o][s] stage
    #pragma unroll
    for (int mf = 0; mf < 4; ++mf)
        #pragma unroll
        for (int nf = 0; nf < 2; ++nf)
            #pragma unroll
            for (int r = 0; r < 4; ++r)
                xs[(mf * 16 + lk * 4 + r) * 128 + wv * 32 + nf * 16 + lr]
                    = acc[mf][nf][r];
    __syncthreads();

    // ---- pooled epilogue (identical logic to verified round-3 kernel) ----
    if (ogrp == 0) {
        { // theta rows 0..31 direct
            const int o = tid >> 3, k = (tid & 7) * 16;
            float* dst = theta_o + ((size_t)b * C8_ + o) * HW_ + (size_t)ht * 128 + k;
            #pragma unroll
            for (int u = 0; u < 4; ++u)
                *(float4*)&dst[u * 4] = *(float4*)&xs[o * 128 + k + u * 4];
        }
        { // phi rows 32..63 pooled
            const int o2 = tid >> 3, wq = (tid & 7) * 4;
            float* dst = phi_o + ((size_t)b * C8_ + o2) * P_ + (size_t)ht * 32 + wq;
            #pragma unroll
            for (int u = 0; u < 4; ++u) {
                int w2 = wq + u;
                dst[u] = fmaxf(fmaxf(xs[(32 + o2) * 128 + 2 * w2],
                                     xs[(32 + o2) * 128 + 2 * w2 + 1]),
                               fmaxf(xs[(32 + o2) * 128 + 64 + 2 * w2],
                                     xs[(32 + o2) * 128 + 64 + 2 * w2 + 1]));
            }
        }
    } else {
        const int base = (ogrp - 1) * 64;
        const int o = tid >> 2, wq = (tid & 3) * 8;
        float* dst = g_o + ((size_t)b * C2_ + base + o) * P_ + (size_t)ht * 32 + wq;
        #pragma unroll
        for (int u = 0; u < 8; ++u) {
            int w2 = wq + u;
            dst[u] = fmaxf(fmaxf(xs[o * 128 + 2 * w2], xs[o * 128 + 2 * w2 + 1]),
                           fmaxf(xs[o * 128 + 64 + 2 * w2], xs[o * 128 + 64 + 2 * w2 + 1]));
        }
    }
}

// ---------------------------------------------------------------------------
// K2: W_og[b] = w_o[256,128] @ g[b][128,1024]  -> bf16 output.
// (verbatim round-3, verified)
// ---------------------------------------------------------------------------
__global__ __launch_bounds__(256) void k2_wog(
    const float* __restrict__ w_o, const float* __restrict__ g,
    unsigned short* __restrict__ wog)
{
    const int p0 = blockIdx.x * 64, cb = blockIdx.y, b = blockIdx.z;
    const int tid = threadIdx.x, wv = tid >> 6, lane = tid & 63;
    __shared__ float wls[64][128];  // [co][c2]  32KB
    __shared__ float gls[128][64];  // [c2][p]   32KB

    {
        const int o = tid >> 2, q = (tid & 3) * 32;
        const float* src = w_o + (size_t)(cb * 64 + o) * 128 + q;
        #pragma unroll
        for (int u = 0; u < 8; ++u)
            *(float4*)&wls[o][q + u * 4] = *(const float4*)&src[u * 4];
        const int c2 = tid >> 1, h = (tid & 1) * 32;
        const float* gsrc = g + ((size_t)b * C2_ + c2) * P_ + p0 + h;
        #pragma unroll
        for (int u = 0; u < 8; ++u)
            *(float4*)&gls[c2][h + u * 4] = *(const float4*)&gsrc[u * 4];
    }
    __syncthreads();

    float acc[16] = {};
    for (int k4 = 0; k4 < 32; ++k4) {
        float gk[4];
        #pragma unroll
        for (int kk = 0; kk < 4; ++kk) gk[kk] = gls[k4 * 4 + kk][lane];
        #pragma unroll
        for (int i = 0; i < 16; ++i) {
            float4 w4 = *(const float4*)&wls[wv * 16 + i][k4 * 4];
            acc[i] += w4.x * gk[0] + w4.y * gk[1] + w4.z * gk[2] + w4.w * gk[3];
        }
    }
    #pragma unroll
    for (int i = 0; i < 16; ++i)
        wog[((size_t)b * C_ + cb * 64 + wv * 16 + i) * P_ + p0 + lane] = f2bf(acc[i]);
}

// ---------------------------------------------------------------------------
// K3: scores + softmax -> beta (bf16).  (verbatim round-3, verified)
// ---------------------------------------------------------------------------
__global__ __launch_bounds__(256) void k3_softmax(
    const float* __restrict__ theta, const float* __restrict__ phi,
    unsigned short* __restrict__ beta)
{
    const int t0 = blockIdx.x * 16, b = blockIdx.y;
    const int tid = threadIdx.x, wv = tid >> 6, lane = tid & 63;
    __shared__ float th[32][16];    // [c][t]   2KB
    __shared__ float ph[32][256];   // [c][p]   32KB

    if (tid < 128) {
        const int c = tid >> 2, tq = (tid & 3) * 4;
        *(float4*)&th[c][tq] =
            *(const float4*)&theta[((size_t)b * C8_ + c) * HW_ + t0 + tq];
    }

    float s[4][16] = {};
    #pragma unroll
    for (int ch = 0; ch < 4; ++ch) {
        __syncthreads();
        {
            const int c = tid >> 3, p8 = (tid & 7) * 4;
            const float* src = phi + ((size_t)b * C8_ + c) * P_ + ch * 256;
            #pragma unroll
            for (int u = 0; u < 8; ++u)
                *(float4*)&ph[c][p8 + u * 32] = *(const float4*)&src[p8 + u * 32];
        }
        __syncthreads();
        for (int c = 0; c < 32; ++c) {
            float4 pv = *(const float4*)&ph[c][lane * 4];
            #pragma unroll
            for (int r = 0; r < 4; ++r) {
                float tv = th[c][wv * 4 + r];
                s[r][ch * 4 + 0] += tv * pv.x;
                s[r][ch * 4 + 1] += tv * pv.y;
                s[r][ch * 4 + 2] += tv * pv.z;
                s[r][ch * 4 + 3] += tv * pv.w;
            }
        }
    }

    #pragma unroll
    for (int r = 0; r < 4; ++r) {
        float m = s[r][0];
        #pragma unroll
        for (int q = 1; q < 16; ++q) m = fmaxf(m, s[r][q]);
        #pragma unroll
        for (int off = 32; off > 0; off >>= 1) m = fmaxf(m, __shfl_xor(m, off));
        float sum = 0.f;
        #pragma unroll
        for (int q = 0; q < 16; ++q) { s[r][q] = __expf(s[r][q] - m); sum += s[r][q]; }
        #pragma unroll
        for (int off = 32; off > 0; off >>= 1) sum += __shfl_xor(sum, off);
        const float rl = 1.0f / sum;
        unsigned short* dst = beta + ((size_t)b * HW_ + t0 + wv * 4 + r) * P_;
        #pragma unroll
        for (int ch = 0; ch < 4; ++ch)
            beta_store4(&dst[ch * 256 + lane * 4],
                        s[r][ch * 4 + 0] * rl, s[r][ch * 4 + 1] * rl,
                        s[r][ch * 4 + 2] * rl, s[r][ch * 4 + 3] * rl);
    }
}

// ---------------------------------------------------------------------------
// K4: out = gamma * (W_og @ beta^T) + x, bf16 MFMA.  (verbatim round-3)
// ---------------------------------------------------------------------------
__global__ __launch_bounds__(256) void k4_mfma(
    const unsigned short* __restrict__ wog, const unsigned short* __restrict__ beta,
    const float* __restrict__ x, const float* __restrict__ gamma_p,
    float* __restrict__ out)
{
    const int t0 = blockIdx.x * 128, c0 = blockIdx.y * 128, b = blockIdx.z;
    const int tid = threadIdx.x, wv = tid >> 6, lane = tid & 63;
    const int wm = wv >> 1, wn = wv & 1;
    const int lr = lane & 15, lk = lane >> 4;
    __shared__ unsigned short As[128 * 64];
    __shared__ unsigned short Bs[128 * 64];

    f32x4 acc[4][4] = {};
    const unsigned short* wog_b  = wog  + ((size_t)b * C_  + c0) * P_;
    const unsigned short* beta_b = beta + ((size_t)b * HW_ + t0) * P_;

    for (int p0 = 0; p0 < 1024; p0 += 64) {
        __syncthreads();
        #pragma unroll
        for (int ch = 0; ch < 4; ++ch) {
            const int i16 = ch * 256 + tid;
            const int row = i16 >> 3, cb8 = i16 & 7;
            GLOAD_LDS(wog_b  + (size_t)row * P_ + p0 + cb8 * 8, &As[i16 * 8]);
            GLOAD_LDS(beta_b + (size_t)row * P_ + p0 + cb8 * 8, &Bs[i16 * 8]);
        }
        __syncthreads();

        #pragma unroll
        for (int ks = 0; ks < 2; ++ks) {
            bf16x8 af[4], bfr[4];
            #pragma unroll
            for (int mf = 0; mf < 4; ++mf)
                af[mf] = *(const bf16x8*)&As[(wm * 64 + mf * 16 + lr) * 64 + ks * 32 + lk * 8];
            #pragma unroll
            for (int nf = 0; nf < 4; ++nf)
                bfr[nf] = *(const bf16x8*)&Bs[(wn * 64 + nf * 16 + lr) * 64 + ks * 32 + lk * 8];
            #pragma unroll
            for (int mf = 0; mf < 4; ++mf)
                #pragma unroll
                for (int nf = 0; nf < 4; ++nf)
                    acc[mf][nf] = __builtin_amdgcn_mfma_f32_16x16x32_bf16(
                        af[mf], bfr[nf], acc[mf][nf], 0, 0, 0);
        }
    }

    const float gm = gamma_p[0];
    #pragma unroll
    for (int mf = 0; mf < 4; ++mf) {
        #pragma unroll
        for (int r = 0; r < 4; ++r) {
            const int co = c0 + wm * 64 + mf * 16 + lk * 4 + r;
            const size_t rowoff = ((size_t)b * C_ + co) * HW_;
            #pragma unroll
            for (int nf = 0; nf < 4; ++nf) {
                const int t = t0 + wn * 64 + nf * 16 + lr;
                out[rowoff + t] = gm * acc[mf][nf][r] + x[rowoff + t];
            }
        }
    }
}

// ---------------------------------------------------------------------------
extern "C" void kernel_launch(void* const* d_in, const int* in_sizes, int n_in,
                              void* d_out, int out_size, void* d_ws, size_t ws_size,
                              hipStream_t stream)
{
    const float* x       = (const float*)d_in[0];
    const float* w_theta = (const float*)d_in[1];
    const float* w_phi   = (const float*)d_in[2];
    const float* w_g     = (const float*)d_in[3];
    const float* w_o     = (const float*)d_in[4];
    const float* gamma   = (const float*)d_in[5];
    float* out = (float*)d_out;
    float* ws  = (float*)d_ws;

    float* theta          = ws + WS_THETA;
    float* phi            = ws + WS_PHI;
    float* g              = ws + WS_G;
    unsigned short* wog   = (unsigned short*)(ws + WS_WOG);
    unsigned short* beta  = (unsigned short*)(ws + WS_BETA);

    k1_proj<<<dim3(32, 3, 16), 256, 0, stream>>>(x, w_theta, w_phi, w_g,
                                                 theta, phi, g);
    k2_wog<<<dim3(16, 4, 16), 256, 0, stream>>>(w_o, g, wog);
    k3_softmax<<<dim3(256, 16), 256, 0, stream>>>(theta, phi, beta);
    k4_mfma<<<dim3(32, 2, 16), 256, 0, stream>>>(wog, beta, x, gamma, out);
}

// Round 7
// 321.028 us; speedup vs baseline: 1.1719x; 1.0341x over previous
//
#include <hip/hip_runtime.h>
#include <stdint.h>

// ---------------------------------------------------------------------------
// SelfAttentionBlock (BigGAN-style), B=16 C=256 H=W=64.
//   thetaT = (w_theta@x)^T        [B,4096,32]  (fp32, split-bf16 MFMA, k1)
//   phiT   = pool2x2(w_phi@x)^T   [B,1024,32]  (fp32, split-bf16 MFMA, k1)
//   g      = pool2x2(w_g@x)       [B,128,1024] (fp32, split-bf16 MFMA, k1)
//   beta   = softmax(thetaT phiT^T) [B,4096,1024] (bf16, split-bf16 MFMA k3)
//   W_og   = w_o @ g              [B,256,1024] (bf16, k2)
//   out    = gamma * (W_og @ beta^T) + x       (fp32, bf16-MFMA k4)
//
// Numerics: scores via 3-term split-bf16 (~1e-4) -> fp32 softmax; only PV
// operands (beta, W_og) are plain bf16. Verified profile: absmax 0.031.
// ---------------------------------------------------------------------------

#define B_  16
#define C_  256
#define HW_ 4096
#define C8_ 32
#define C2_ 128
#define P_  1024

// ws layout in float units (thetaT/phiT same sizes as old theta/phi)
#define WS_THETA 0u
#define WS_PHI   2097152u          // + 16*4096*32        (thetaT fp32)
#define WS_G     2621440u          // + 16*1024*32        (phiT fp32)
#define WS_WOG   4718592u          // + 16*128*1024       (g fp32)
#define WS_BETA  6815744u          // + 16*256*1024/2     (wog bf16)

// ---- bf16 helpers ---------------------------------------------------------
__device__ inline unsigned short f2bf(float f) {          // RNE
    unsigned int u = __builtin_bit_cast(unsigned int, f);
    u = (u + 0x7fffu + ((u >> 16) & 1u)) >> 16;
    return (unsigned short)u;
}
__device__ inline void beta_store4(unsigned short* p, float a, float b, float c, float d) {
    ushort4 v; v.x = f2bf(a); v.y = f2bf(b); v.z = f2bf(c); v.w = f2bf(d);
    *(ushort4*)p = v;
}
// truncation split: f = hi + lo + O(2^-16 |f|)
__device__ inline void splitbf(float f, unsigned short& h, unsigned short& l) {
    unsigned u = __builtin_bit_cast(unsigned, f);
    h = (unsigned short)(u >> 16);
    float lof = f - __builtin_bit_cast(float, u & 0xffff0000u);
    l = (unsigned short)(__builtin_bit_cast(unsigned, lof) >> 16);
}

typedef __attribute__((ext_vector_type(8))) short bf16x8;
typedef __attribute__((ext_vector_type(8))) unsigned short u16x8;
typedef __attribute__((ext_vector_type(4))) float f32x4;

// global -> LDS direct staging, 16B per lane, linear LDS dest (lane-ordered)
#define GLOAD_LDS(gsrc, ldst) __builtin_amdgcn_global_load_lds( \
    (__attribute__((address_space(1))) void*)(uintptr_t)(const void*)(gsrc), \
    (__attribute__((address_space(3))) void*)(ldst), 16, 0, 0)

// ---------------------------------------------------------------------------
// K1: projections + fused 2x2 maxpool via split-bf16 MFMA (16x16x32).
// Main loop identical to round-6 verified kernel. Epilogue (ogrp 0) now
// writes TRANSPOSED thetaT [s][32 c] and phiT [p][32 c] so k3 can read
// k-contiguous MFMA fragments directly. g path unchanged (k2 wants [c2][p]).
// ---------------------------------------------------------------------------
__global__ __launch_bounds__(256, 3) void k1_proj(
    const float* __restrict__ x, const float* __restrict__ w_theta,
    const float* __restrict__ w_phi, const float* __restrict__ w_g,
    float* __restrict__ thetaT_o, float* __restrict__ phiT_o, float* __restrict__ g_o)
{
    const int ht = blockIdx.x, ogrp = blockIdx.y, b = blockIdx.z;
    const int tid = threadIdx.x;
    const int lane = tid & 63, wv = tid >> 6;
    const int lr = lane & 15, lk = lane >> 4;

    __shared__ float xs[64 * 128];            // fp32 [c][s]; later [o][s] stage
    __shared__ unsigned short WHs[64 * 72];   // [o][c] hi (pad 72)
    __shared__ unsigned short WLs[64 * 72];   // [o][c] lo

    const float* xb = x + ((size_t)b * C_) * HW_ + (size_t)ht * 128;
    const int c_ld = tid >> 2;            // x stage: c row 0..63
    const int sseg = (tid & 3) * 32;      // x stage: s segment
    const int o_ld = tid >> 2;            // W stage: o row 0..63
    const int cseg = (tid & 3) * 16;      // W stage: c segment

    const float* wsrc;
    if (ogrp == 0) wsrc = (o_ld < 32) ? (w_theta + o_ld * 256)
                                      : (w_phi + (o_ld - 32) * 256);
    else if (ogrp == 1) wsrc = w_g + o_ld * 256;
    else wsrc = w_g + (o_ld + 64) * 256;

    f32x4 acc[4][2] = {};

    for (int kc = 0; kc < 4; ++kc) {
        const int c0 = kc * 64;
        __syncthreads();
        { // x chunk [64 c][128 s] -> fp32 LDS
            const float* src = xb + (size_t)(c0 + c_ld) * HW_ + sseg;
            #pragma unroll
            for (int u = 0; u < 8; ++u)
                *(float4*)&xs[c_ld * 128 + sseg + u * 4] = *(const float4*)&src[u * 4];
        }
        { // W chunk [64 o][64 c] -> split-bf16 LDS
            #pragma unroll
            for (int h = 0; h < 2; ++h) {
                u16x8 hi, lo;
                #pragma unroll
                for (int e = 0; e < 8; ++e) {
                    unsigned short hh, ll;
                    splitbf(wsrc[c0 + cseg + h * 8 + e], hh, ll);
                    hi[e] = hh; lo[e] = ll;
                }
                *(u16x8*)&WHs[o_ld * 72 + cseg + h * 8] = hi;
                *(u16x8*)&WLs[o_ld * 72 + cseg + h * 8] = lo;
            }
        }
        __syncthreads();

        #pragma unroll
        for (int ks = 0; ks < 2; ++ks) {
            bf16x8 Ah[4], Al[4];
            #pragma unroll
            for (int mf = 0; mf < 4; ++mf) {
                Ah[mf] = *(const bf16x8*)&WHs[(mf * 16 + lr) * 72 + ks * 32 + lk * 8];
                Al[mf] = *(const bf16x8*)&WLs[(mf * 16 + lr) * 72 + ks * 32 + lk * 8];
            }
            #pragma unroll
            for (int nf = 0; nf < 2; ++nf) {
                const int s = wv * 32 + nf * 16 + lr;
                u16x8 hi, lo;
                #pragma unroll
                for (int e = 0; e < 8; ++e) {
                    unsigned short hh, ll;
                    splitbf(xs[(ks * 32 + lk * 8 + e) * 128 + s], hh, ll);
                    hi[e] = hh; lo[e] = ll;
                }
                const bf16x8 Bh = __builtin_bit_cast(bf16x8, hi);
                const bf16x8 Bl = __builtin_bit_cast(bf16x8, lo);
                #pragma unroll
                for (int mf = 0; mf < 4; ++mf) {
                    acc[mf][nf] = __builtin_amdgcn_mfma_f32_16x16x32_bf16(
                        Ah[mf], Bh, acc[mf][nf], 0, 0, 0);
                    acc[mf][nf] = __builtin_amdgcn_mfma_f32_16x16x32_bf16(
                        Ah[mf], Bl, acc[mf][nf], 0, 0, 0);
                    acc[mf][nf] = __builtin_amdgcn_mfma_f32_16x16x32_bf16(
                        Al[mf], Bh, acc[mf][nf], 0, 0, 0);
                }
            }
        }
    }

    __syncthreads();   // all fragment reads done -> xs reusable as [o][s] stage
    #pragma unroll
    for (int mf = 0; mf < 4; ++mf)
        #pragma unroll
        for (int nf = 0; nf < 2; ++nf)
            #pragma unroll
            for (int r = 0; r < 4; ++r)
                xs[(mf * 16 + lk * 4 + r) * 128 + wv * 32 + nf * 16 + lr]
                    = acc[mf][nf][r];
    __syncthreads();

    if (ogrp == 0) {
        { // thetaT rows (ht*128 + s), 32 c each: gather xs columns
            const int s = tid >> 1, o16 = (tid & 1) * 16;
            float* dst = thetaT_o + ((size_t)b * HW_ + (size_t)ht * 128 + s) * 32 + o16;
            #pragma unroll
            for (int u = 0; u < 4; ++u) {
                float4 v;
                v.x = xs[(o16 + u * 4 + 0) * 128 + s];
                v.y = xs[(o16 + u * 4 + 1) * 128 + s];
                v.z = xs[(o16 + u * 4 + 2) * 128 + s];
                v.w = xs[(o16 + u * 4 + 3) * 128 + s];
                *(float4*)&dst[u * 4] = v;
            }
        }
        { // phiT rows (ht*32 + w2), pooled from xs rows 32..63
            const int o2 = tid >> 3, wq = (tid & 7) * 4;
            #pragma unroll
            for (int u = 0; u < 4; ++u) {
                int w2 = wq + u;
                float pv = fmaxf(fmaxf(xs[(32 + o2) * 128 + 2 * w2],
                                       xs[(32 + o2) * 128 + 2 * w2 + 1]),
                                 fmaxf(xs[(32 + o2) * 128 + 64 + 2 * w2],
                                       xs[(32 + o2) * 128 + 64 + 2 * w2 + 1]));
                phiT_o[((size_t)b * P_ + (size_t)ht * 32 + w2) * 32 + o2] = pv;
            }
        }
    } else {
        const int base = (ogrp - 1) * 64;
        const int o = tid >> 2, wq = (tid & 3) * 8;
        float* dst = g_o + ((size_t)b * C2_ + base + o) * P_ + (size_t)ht * 32 + wq;
        #pragma unroll
        for (int u = 0; u < 8; ++u) {
            int w2 = wq + u;
            dst[u] = fmaxf(fmaxf(xs[o * 128 + 2 * w2], xs[o * 128 + 2 * w2 + 1]),
                           fmaxf(xs[o * 128 + 64 + 2 * w2], xs[o * 128 + 64 + 2 * w2 + 1]));
        }
    }
}

// ---------------------------------------------------------------------------
// K2: W_og[b] = w_o[256,128] @ g[b][128,1024]  -> bf16.  (verbatim, verified)
// ---------------------------------------------------------------------------
__global__ __launch_bounds__(256) void k2_wog(
    const float* __restrict__ w_o, const float* __restrict__ g,
    unsigned short* __restrict__ wog)
{
    const int p0 = blockIdx.x * 64, cb = blockIdx.y, b = blockIdx.z;
    const int tid = threadIdx.x, wv = tid >> 6, lane = tid & 63;
    __shared__ float wls[64][128];  // [co][c2]  32KB
    __shared__ float gls[128][64];  // [c2][p]   32KB

    {
        const int o = tid >> 2, q = (tid & 3) * 32;
        const float* src = w_o + (size_t)(cb * 64 + o) * 128 + q;
        #pragma unroll
        for (int u = 0; u < 8; ++u)
            *(float4*)&wls[o][q + u * 4] = *(const float4*)&src[u * 4];
        const int c2 = tid >> 1, h = (tid & 1) * 32;
        const float* gsrc = g + ((size_t)b * C2_ + c2) * P_ + p0 + h;
        #pragma unroll
        for (int u = 0; u < 8; ++u)
            *(float4*)&gls[c2][h + u * 4] = *(const float4*)&gsrc[u * 4];
    }
    __syncthreads();

    float acc[16] = {};
    for (int k4 = 0; k4 < 32; ++k4) {
        float gk[4];
        #pragma unroll
        for (int kk = 0; kk < 4; ++kk) gk[kk] = gls[k4 * 4 + kk][lane];
        #pragma unroll
        for (int i = 0; i < 16; ++i) {
            float4 w4 = *(const float4*)&wls[wv * 16 + i][k4 * 4];
            acc[i] += w4.x * gk[0] + w4.y * gk[1] + w4.z * gk[2] + w4.w * gk[3];
        }
    }
    #pragma unroll
    for (int i = 0; i < 16; ++i)
        wog[((size_t)b * C_ + cb * 64 + wv * 16 + i) * P_ + p0 + lane] = f2bf(acc[i]);
}

// ---------------------------------------------------------------------------
// K3': scores via split-bf16 MFMA + fp32 softmax -> beta (bf16).
// grid (256 t-tiles of 16, 16 b), block 256 (4 waves; wave wv owns 64 p per
// 256-p chunk). Inputs thetaT [4096][32], phiT [1024][32] (k-contiguous).
// LDS: phB hi/lo [256 p][40 c-pad] ushort (40KB), thA hi/lo [16][40] (2.5KB),
// red [16][4] f32. MFMA: A=thetaT rows (m=t), B=phiT rows (n=p), K=32 in one
// 16x16x32 shot; 3-term split => scores err ~1e-4. C/D (k4-verified):
// col=lane&15 -> p, row=(lane>>4)*4+reg -> t.
// Softmax: 16-lane-group shfl_xor reduce + cross-wave LDS combine.
// ---------------------------------------------------------------------------
__global__ __launch_bounds__(256, 3) void k3_mfma(
    const float* __restrict__ thetaT, const float* __restrict__ phiT,
    unsigned short* __restrict__ beta)
{
    const int t0 = blockIdx.x * 16, b = blockIdx.y;
    const int tid = threadIdx.x, wv = tid >> 6, lane = tid & 63;
    const int lr = lane & 15, lk = lane >> 4;

    __shared__ __align__(16) char sm[44032];
    unsigned short* phH = (unsigned short*)sm;            // [256][40]
    unsigned short* phL = (unsigned short*)(sm + 20480);  // [256][40]
    unsigned short* thH = (unsigned short*)(sm + 40960);  // [16][40]
    unsigned short* thL = (unsigned short*)(sm + 42240);  // [16][40]
    float* red = (float*)(sm + 43520);                    // [16][4]

    // ---- stage thA (once): [16 t][32 c] split-bf16 ----
    if (tid < 128) {
        const int t = tid >> 3, c4 = (tid & 7) * 4;
        float4 v = *(const float4*)&thetaT[((size_t)b * HW_ + t0 + t) * 32 + c4];
        ushort4 hv, lv;
        splitbf(v.x, hv.x, lv.x); splitbf(v.y, hv.y, lv.y);
        splitbf(v.z, hv.z, lv.z); splitbf(v.w, hv.w, lv.w);
        *(ushort4*)&thH[t * 40 + c4] = hv;
        *(ushort4*)&thL[t * 40 + c4] = lv;
    }

    f32x4 sc[16];

    #pragma unroll
    for (int ch = 0; ch < 4; ++ch) {
        __syncthreads();   // prev chunk MFMA done (and thA visible on ch=0)
        { // stage phB chunk: thread -> full row p = tid
            const float* src = &phiT[((size_t)b * P_ + ch * 256 + tid) * 32];
            #pragma unroll
            for (int g2 = 0; g2 < 4; ++g2) {
                float4 a = *(const float4*)&src[g2 * 8];
                float4 b4 = *(const float4*)&src[g2 * 8 + 4];
                u16x8 hi, lo;
                unsigned short hh, ll;
                splitbf(a.x, hh, ll);  hi[0] = hh; lo[0] = ll;
                splitbf(a.y, hh, ll);  hi[1] = hh; lo[1] = ll;
                splitbf(a.z, hh, ll);  hi[2] = hh; lo[2] = ll;
                splitbf(a.w, hh, ll);  hi[3] = hh; lo[3] = ll;
                splitbf(b4.x, hh, ll); hi[4] = hh; lo[4] = ll;
                splitbf(b4.y, hh, ll); hi[5] = hh; lo[5] = ll;
                splitbf(b4.z, hh, ll); hi[6] = hh; lo[6] = ll;
                splitbf(b4.w, hh, ll); hi[7] = hh; lo[7] = ll;
                *(u16x8*)&phH[tid * 40 + g2 * 8] = hi;
                *(u16x8*)&phL[tid * 40 + g2 * 8] = lo;
            }
        }
        __syncthreads();

        const bf16x8 Ah = *(const bf16x8*)&thH[lr * 40 + lk * 8];
        const bf16x8 Al = *(const bf16x8*)&thL[lr * 40 + lk * 8];
        #pragma unroll
        for (int q = 0; q < 4; ++q) {
            const int prow = wv * 64 + q * 16 + lr;
            const bf16x8 Bh = *(const bf16x8*)&phH[prow * 40 + lk * 8];
            const bf16x8 Bl = *(const bf16x8*)&phL[prow * 40 + lk * 8];
            f32x4 a = {};
            a = __builtin_amdgcn_mfma_f32_16x16x32_bf16(Ah, Bh, a, 0, 0, 0);
            a = __builtin_amdgcn_mfma_f32_16x16x32_bf16(Ah, Bl, a, 0, 0, 0);
            a = __builtin_amdgcn_mfma_f32_16x16x32_bf16(Al, Bh, a, 0, 0, 0);
            sc[ch * 4 + q] = a;
        }
    }

    // ---- softmax over p (rows t = lk*4 + r) ----
    float mrow[4], rl[4];
    #pragma unroll
    for (int r = 0; r < 4; ++r) {
        float m = sc[0][r];
        #pragma unroll
        for (int qg = 1; qg < 16; ++qg) m = fmaxf(m, sc[qg][r]);
        #pragma unroll
        for (int off = 1; off < 16; off <<= 1) m = fmaxf(m, __shfl_xor(m, off));
        mrow[r] = m;
    }
    __syncthreads();          // red free (previous use: none yet, but ordered)
    if (lr == 0) {
        #pragma unroll
        for (int r = 0; r < 4; ++r) red[(lk * 4 + r) * 4 + wv] = mrow[r];
    }
    __syncthreads();
    #pragma unroll
    for (int r = 0; r < 4; ++r) {
        const int t = lk * 4 + r;
        mrow[r] = fmaxf(fmaxf(red[t * 4 + 0], red[t * 4 + 1]),
                        fmaxf(red[t * 4 + 2], red[t * 4 + 3]));
    }
    __syncthreads();          // before red reuse for sums

    float ssum[4];
    #pragma unroll
    for (int r = 0; r < 4; ++r) {
        float s = 0.f;
        #pragma unroll
        for (int qg = 0; qg < 16; ++qg) {
            float e = __expf(sc[qg][r] - mrow[r]);
            sc[qg][r] = e; s += e;
        }
        #pragma unroll
        for (int off = 1; off < 16; off <<= 1) s += __shfl_xor(s, off);
        ssum[r] = s;
    }
    if (lr == 0) {
        #pragma unroll
        for (int r = 0; r < 4; ++r) red[(lk * 4 + r) * 4 + wv] = ssum[r];
    }
    __syncthreads();
    #pragma unroll
    for (int r = 0; r < 4; ++r) {
        const int t = lk * 4 + r;
        rl[r] = 1.0f / (red[t * 4 + 0] + red[t * 4 + 1] +
                        red[t * 4 + 2] + red[t * 4 + 3]);
    }

    // ---- beta store (bf16): p = (qg>>2)*256 + wv*64 + (qg&3)*16 + lr ----
    unsigned short* bb = beta + ((size_t)b * HW_ + t0) * P_;
    #pragma unroll
    for (int qg = 0; qg < 16; ++qg) {
        const int p = (qg >> 2) * 256 + wv * 64 + (qg & 3) * 16 + lr;
        #pragma unroll
        for (int r = 0; r < 4; ++r)
            bb[(size_t)(lk * 4 + r) * P_ + p] = f2bf(sc[qg][r] * rl[r]);
    }
}

// ---------------------------------------------------------------------------
// K4: out = gamma * (W_og @ beta^T) + x, bf16 MFMA.  (verbatim, verified)
// ---------------------------------------------------------------------------
__global__ __launch_bounds__(256) void k4_mfma(
    const unsigned short* __restrict__ wog, const unsigned short* __restrict__ beta,
    const float* __restrict__ x, const float* __restrict__ gamma_p,
    float* __restrict__ out)
{
    const int t0 = blockIdx.x * 128, c0 = blockIdx.y * 128, b = blockIdx.z;
    const int tid = threadIdx.x, wv = tid >> 6, lane = tid & 63;
    const int wm = wv >> 1, wn = wv & 1;
    const int lr = lane & 15, lk = lane >> 4;
    __shared__ unsigned short As[128 * 64];
    __shared__ unsigned short Bs[128 * 64];

    f32x4 acc[4][4] = {};
    const unsigned short* wog_b  = wog  + ((size_t)b * C_  + c0) * P_;
    const unsigned short* beta_b = beta + ((size_t)b * HW_ + t0) * P_;

    for (int p0 = 0; p0 < 1024; p0 += 64) {
        __syncthreads();
        #pragma unroll
        for (int ch = 0; ch < 4; ++ch) {
            const int i16 = ch * 256 + tid;
            const int row = i16 >> 3, cb8 = i16 & 7;
            GLOAD_LDS(wog_b  + (size_t)row * P_ + p0 + cb8 * 8, &As[i16 * 8]);
            GLOAD_LDS(beta_b + (size_t)row * P_ + p0 + cb8 * 8, &Bs[i16 * 8]);
        }
        __syncthreads();

        #pragma unroll
        for (int ks = 0; ks < 2; ++ks) {
            bf16x8 af[4], bfr[4];
            #pragma unroll
            for (int mf = 0; mf < 4; ++mf)
                af[mf] = *(const bf16x8*)&As[(wm * 64 + mf * 16 + lr) * 64 + ks * 32 + lk * 8];
            #pragma unroll
            for (int nf = 0; nf < 4; ++nf)
                bfr[nf] = *(const bf16x8*)&Bs[(wn * 64 + nf * 16 + lr) * 64 + ks * 32 + lk * 8];
            #pragma unroll
            for (int mf = 0; mf < 4; ++mf)
                #pragma unroll
                for (int nf = 0; nf < 4; ++nf)
                    acc[mf][nf] = __builtin_amdgcn_mfma_f32_16x16x32_bf16(
                        af[mf], bfr[nf], acc[mf][nf], 0, 0, 0);
        }
    }

    const float gm = gamma_p[0];
    #pragma unroll
    for (int mf = 0; mf < 4; ++mf) {
        #pragma unroll
        for (int r = 0; r < 4; ++r) {
            const int co = c0 + wm * 64 + mf * 16 + lk * 4 + r;
            const size_t rowoff = ((size_t)b * C_ + co) * HW_;
            #pragma unroll
            for (int nf = 0; nf < 4; ++nf) {
                const int t = t0 + wn * 64 + nf * 16 + lr;
                out[rowoff + t] = gm * acc[mf][nf][r] + x[rowoff + t];
            }
        }
    }
}

// ---------------------------------------------------------------------------
extern "C" void kernel_launch(void* const* d_in, const int* in_sizes, int n_in,
                              void* d_out, int out_size, void* d_ws, size_t ws_size,
                              hipStream_t stream)
{
    const float* x       = (const float*)d_in[0];
    const float* w_theta = (const float*)d_in[1];
    const float* w_phi   = (const float*)d_in[2];
    const float* w_g     = (const float*)d_in[3];
    const float* w_o     = (const float*)d_in[4];
    const float* gamma   = (const float*)d_in[5];
    float* out = (float*)d_out;
    float* ws  = (float*)d_ws;

    float* thetaT         = ws + WS_THETA;
    float* phiT           = ws + WS_PHI;
    float* g              = ws + WS_G;
    unsigned short* wog   = (unsigned short*)(ws + WS_WOG);
    unsigned short* beta  = (unsigned short*)(ws + WS_BETA);

    k1_proj<<<dim3(32, 3, 16), 256, 0, stream>>>(x, w_theta, w_phi, w_g,
                                                 thetaT, phiT, g);
    k2_wog<<<dim3(16, 4, 16), 256, 0, stream>>>(w_o, g, wog);
    k3_mfma<<<dim3(256, 16), 256, 0, stream>>>(thetaT, phiT, beta);
    k4_mfma<<<dim3(32, 2, 16), 256, 0, stream>>>(wog, beta, x, gamma, out);
}

// Round 10
// 288.272 us; speedup vs baseline: 1.3051x; 1.1136x over previous
//
#include <hip/hip_runtime.h>
#include <stdint.h>

// ---------------------------------------------------------------------------
// SelfAttentionBlock (BigGAN-style), B=16 C=256 H=W=64.
//   thetaT = (w_theta@x)^T   [B,4096,32] split-bf16 hi/lo (k1)
//   phiT   = pool(w_phi@x)^T [B,1024,32] split-bf16 hi/lo (k1)
//   g      = pool(w_g@x)     [B,128,1024] fp32 (k1)
//   beta   = softmax(thetaT phiT^T) [B,4096,1024] bf16 (k3, split-bf16 MFMA)
//   W_og   = w_o @ g         [B,256,1024] bf16 (k2)
//   out    = gamma * (W_og @ beta^T) + x  (k4, bf16 MFMA, swizzled LDS)
//
// Numerics: scores via 3-term split-bf16 (~1e-4) -> fp32 softmax; only PV
// operands (beta, W_og) plain bf16. Verified profile: absmax 0.03125.
// ---------------------------------------------------------------------------

#define B_  16
#define C_  256
#define HW_ 4096
#define C8_ 32
#define C2_ 128
#define P_  1024

// ws layout in float units
#define WS_THH  0u                 // thetaT hi: 16*4096*32 us = 1,048,576 fl
#define WS_THL  1048576u           // thetaT lo
#define WS_PHH  2097152u           // phiT hi: 16*1024*32 us = 262,144 fl
#define WS_PHL  2359296u           // phiT lo
#define WS_G    2621440u           // g fp32: 16*128*1024
#define WS_WOG  4718592u           // wog bf16: 16*256*1024 us
#define WS_BETA 6815744u           // beta bf16: 16*4096*1024 us

// ---- bf16 helpers ---------------------------------------------------------
__device__ inline unsigned short f2bf(float f) {          // RNE
    unsigned int u = __builtin_bit_cast(unsigned int, f);
    u = (u + 0x7fffu + ((u >> 16) & 1u)) >> 16;
    return (unsigned short)u;
}
// truncation split: f = hi + lo + O(2^-16 |f|)
__device__ inline void splitbf(float f, unsigned short& h, unsigned short& l) {
    unsigned u = __builtin_bit_cast(unsigned, f);
    h = (unsigned short)(u >> 16);
    float lof = f - __builtin_bit_cast(float, u & 0xffff0000u);
    l = (unsigned short)(__builtin_bit_cast(unsigned, lof) >> 16);
}

typedef __attribute__((ext_vector_type(8))) short bf16x8;
typedef __attribute__((ext_vector_type(8))) unsigned short u16x8;
typedef __attribute__((ext_vector_type(4))) float f32x4;

// global -> LDS direct staging, 16B/lane, LINEAR lane-ordered LDS dest.
#define GLOAD_LDS(gsrc, ldst) __builtin_amdgcn_global_load_lds( \
    (__attribute__((address_space(1))) void*)(uintptr_t)(const void*)(gsrc), \
    (__attribute__((address_space(3))) void*)(ldst), 16, 0, 0)

// ---------------------------------------------------------------------------
// K1: projections + fused 2x2 maxpool via split-bf16 MFMA (16x16x32).
// Main loop identical to round-6/7 verified kernel. Epilogue ogrp 0 emits
// SPLIT hi/lo bf16 thetaT/phiT (k-contiguous rows) so k3 stages via pure
// global_load_lds. g path unchanged.
// ---------------------------------------------------------------------------
__global__ __launch_bounds__(256, 3) void k1_proj(
    const float* __restrict__ x, const float* __restrict__ w_theta,
    const float* __restrict__ w_phi, const float* __restrict__ w_g,
    unsigned short* __restrict__ thetaTH, unsigned short* __restrict__ thetaTL,
    unsigned short* __restrict__ phiTH, unsigned short* __restrict__ phiTL,
    float* __restrict__ g_o)
{
    const int ht = blockIdx.x, ogrp = blockIdx.y, b = blockIdx.z;
    const int tid = threadIdx.x;
    const int lane = tid & 63, wv = tid >> 6;
    const int lr = lane & 15, lk = lane >> 4;

    __shared__ float xs[64 * 128];            // fp32 [c][s]; later [o][s] stage
    __shared__ unsigned short WHs[64 * 72];   // [o][c] hi (pad 72)
    __shared__ unsigned short WLs[64 * 72];   // [o][c] lo

    const float* xb = x + ((size_t)b * C_) * HW_ + (size_t)ht * 128;
    const int c_ld = tid >> 2;            // x stage: c row 0..63
    const int sseg = (tid & 3) * 32;      // x stage: s segment
    const int o_ld = tid >> 2;            // W stage: o row 0..63
    const int cseg = (tid & 3) * 16;      // W stage: c segment

    const float* wsrc;
    if (ogrp == 0) wsrc = (o_ld < 32) ? (w_theta + o_ld * 256)
                                      : (w_phi + (o_ld - 32) * 256);
    else if (ogrp == 1) wsrc = w_g + o_ld * 256;
    else wsrc = w_g + (o_ld + 64) * 256;

    f32x4 acc[4][2] = {};

    for (int kc = 0; kc < 4; ++kc) {
        const int c0 = kc * 64;
        __syncthreads();
        { // x chunk [64 c][128 s] -> fp32 LDS
            const float* src = xb + (size_t)(c0 + c_ld) * HW_ + sseg;
            #pragma unroll
            for (int u = 0; u < 8; ++u)
                *(float4*)&xs[c_ld * 128 + sseg + u * 4] = *(const float4*)&src[u * 4];
        }
        { // W chunk [64 o][64 c] -> split-bf16 LDS
            #pragma unroll
            for (int h = 0; h < 2; ++h) {
                u16x8 hi, lo;
                #pragma unroll
                for (int e = 0; e < 8; ++e) {
                    unsigned short hh, ll;
                    splitbf(wsrc[c0 + cseg + h * 8 + e], hh, ll);
                    hi[e] = hh; lo[e] = ll;
                }
                *(u16x8*)&WHs[o_ld * 72 + cseg + h * 8] = hi;
                *(u16x8*)&WLs[o_ld * 72 + cseg + h * 8] = lo;
            }
        }
        __syncthreads();

        #pragma unroll
        for (int ks = 0; ks < 2; ++ks) {
            bf16x8 Ah[4], Al[4];
            #pragma unroll
            for (int mf = 0; mf < 4; ++mf) {
                Ah[mf] = *(const bf16x8*)&WHs[(mf * 16 + lr) * 72 + ks * 32 + lk * 8];
                Al[mf] = *(const bf16x8*)&WLs[(mf * 16 + lr) * 72 + ks * 32 + lk * 8];
            }
            #pragma unroll
            for (int nf = 0; nf < 2; ++nf) {
                const int s = wv * 32 + nf * 16 + lr;
                u16x8 hi, lo;
                #pragma unroll
                for (int e = 0; e < 8; ++e) {
                    unsigned short hh, ll;
                    splitbf(xs[(ks * 32 + lk * 8 + e) * 128 + s], hh, ll);
                    hi[e] = hh; lo[e] = ll;
                }
                const bf16x8 Bh = __builtin_bit_cast(bf16x8, hi);
                const bf16x8 Bl = __builtin_bit_cast(bf16x8, lo);
                #pragma unroll
                for (int mf = 0; mf < 4; ++mf) {
                    acc[mf][nf] = __builtin_amdgcn_mfma_f32_16x16x32_bf16(
                        Ah[mf], Bh, acc[mf][nf], 0, 0, 0);
                    acc[mf][nf] = __builtin_amdgcn_mfma_f32_16x16x32_bf16(
                        Ah[mf], Bl, acc[mf][nf], 0, 0, 0);
                    acc[mf][nf] = __builtin_amdgcn_mfma_f32_16x16x32_bf16(
                        Al[mf], Bh, acc[mf][nf], 0, 0, 0);
                }
            }
        }
    }

    __syncthreads();   // all fragment reads done -> xs reusable as [o][s] stage
    #pragma unroll
    for (int mf = 0; mf < 4; ++mf)
        #pragma unroll
        for (int nf = 0; nf < 2; ++nf)
            #pragma unroll
            for (int r = 0; r < 4; ++r)
                xs[(mf * 16 + lk * 4 + r) * 128 + wv * 32 + nf * 16 + lr]
                    = acc[mf][nf][r];
    __syncthreads();

    if (ogrp == 0) {
        { // thetaT split rows: thread -> row s, half o16
            const int s = tid >> 1, o16 = (tid & 1) * 16;
            u16x8 h0, h1, l0, l1;
            #pragma unroll
            for (int i = 0; i < 8; ++i) {
                unsigned short hh, ll;
                splitbf(xs[(o16 + i) * 128 + s], hh, ll);
                h0[i] = hh; l0[i] = ll;
                splitbf(xs[(o16 + 8 + i) * 128 + s], hh, ll);
                h1[i] = hh; l1[i] = ll;
            }
            const size_t roff = ((size_t)b * HW_ + (size_t)ht * 128 + s) * 32 + o16;
            *(u16x8*)&thetaTH[roff] = h0; *(u16x8*)&thetaTH[roff + 8] = h1;
            *(u16x8*)&thetaTL[roff] = l0; *(u16x8*)&thetaTL[roff + 8] = l1;
        }
        { // phiT split rows, pooled from xs rows 32..63
            const int o2 = tid >> 3, wq = (tid & 7) * 4;
            #pragma unroll
            for (int u = 0; u < 4; ++u) {
                int w2 = wq + u;
                float pv = fmaxf(fmaxf(xs[(32 + o2) * 128 + 2 * w2],
                                       xs[(32 + o2) * 128 + 2 * w2 + 1]),
                                 fmaxf(xs[(32 + o2) * 128 + 64 + 2 * w2],
                                       xs[(32 + o2) * 128 + 64 + 2 * w2 + 1]));
                unsigned short hh, ll;
                splitbf(pv, hh, ll);
                const size_t poff = ((size_t)b * P_ + (size_t)ht * 32 + w2) * 32 + o2;
                phiTH[poff] = hh; phiTL[poff] = ll;
            }
        }
    } else {
        const int base = (ogrp - 1) * 64;
        const int o = tid >> 2, wq = (tid & 3) * 8;
        float* dst = g_o + ((size_t)b * C2_ + base + o) * P_ + (size_t)ht * 32 + wq;
        #pragma unroll
        for (int u = 0; u < 8; ++u) {
            int w2 = wq + u;
            dst[u] = fmaxf(fmaxf(xs[o * 128 + 2 * w2], xs[o * 128 + 2 * w2 + 1]),
                           fmaxf(xs[o * 128 + 64 + 2 * w2], xs[o * 128 + 64 + 2 * w2 + 1]));
        }
    }
}

// ---------------------------------------------------------------------------
// K2: W_og[b] = w_o[256,128] @ g[b][128,1024]  -> bf16.  (verbatim, verified)
// ---------------------------------------------------------------------------
__global__ __launch_bounds__(256) void k2_wog(
    const float* __restrict__ w_o, const float* __restrict__ g,
    unsigned short* __restrict__ wog)
{
    const int p0 = blockIdx.x * 64, cb = blockIdx.y, b = blockIdx.z;
    const int tid = threadIdx.x, wv = tid >> 6, lane = tid & 63;
    __shared__ float wls[64][128];  // [co][c2]  32KB
    __shared__ float gls[128][64];  // [c2][p]   32KB

    {
        const int o = tid >> 2, q = (tid & 3) * 32;
        const float* src = w_o + (size_t)(cb * 64 + o) * 128 + q;
        #pragma unroll
        for (int u = 0; u < 8; ++u)
            *(float4*)&wls[o][q + u * 4] = *(const float4*)&src[u * 4];
        const int c2 = tid >> 1, h = (tid & 1) * 32;
        const float* gsrc = g + ((size_t)b * C2_ + c2) * P_ + p0 + h;
        #pragma unroll
        for (int u = 0; u < 8; ++u)
            *(float4*)&gls[c2][h + u * 4] = *(const float4*)&gsrc[u * 4];
    }
    __syncthreads();

    float acc[16] = {};
    for (int k4 = 0; k4 < 32; ++k4) {
        float gk[4];
        #pragma unroll
        for (int kk = 0; kk < 4; ++kk) gk[kk] = gls[k4 * 4 + kk][lane];
        #pragma unroll
        for (int i = 0; i < 16; ++i) {
            float4 w4 = *(const float4*)&wls[wv * 16 + i][k4 * 4];
            acc[i] += w4.x * gk[0] + w4.y * gk[1] + w4.z * gk[2] + w4.w * gk[3];
        }
    }
    #pragma unroll
    for (int i = 0; i < 16; ++i)
        wog[((size_t)b * C_ + cb * 64 + wv * 16 + i) * P_ + p0 + lane] = f2bf(acc[i]);
}

// ---------------------------------------------------------------------------
// K3: scores (split-bf16 MFMA) + fp32 softmax -> beta (bf16).
// grid (128 t-tiles of 32, 16 b), block 256 (4 waves; wave owns 64 p/chunk).
// Inputs pre-split hi/lo bf16 [*][32] rows -> staging is pure GLOAD_LDS.
// Swizzle (rule-21): LDS dest linear; global source unit j -> j^((row>>1)&3);
// read with same involution. (Bank floor for 64B rows is 8-way; measure
// next round whether LDS path still dominates.)
// ---------------------------------------------------------------------------
__global__ __launch_bounds__(256, 2) void k3_mfma(
    const unsigned short* __restrict__ thH_g, const unsigned short* __restrict__ thL_g,
    const unsigned short* __restrict__ phH_g, const unsigned short* __restrict__ phL_g,
    unsigned short* __restrict__ beta)
{
    const int t0 = blockIdx.x * 32, b = blockIdx.y;
    const int tid = threadIdx.x, wv = tid >> 6, lane = tid & 63;
    const int lr = lane & 15, lk = lane >> 4;

    __shared__ unsigned short thH[32 * 32], thL[32 * 32];   // 2KB each
    __shared__ unsigned short phH[256 * 32], phL[256 * 32]; // 16KB each
    __shared__ float red[32 * 4];

    // ---- stage thA once: 128 16B-units/half; wave-uniform base + lane*16B
    {
        const int u = lane + (wv & 1) * 64;   // 0..127
        const int row = u >> 2, j = u & 3;
        const int gj = j ^ ((row >> 1) & 3);
        const size_t goff = ((size_t)b * HW_ + t0 + row) * 32 + gj * 8;
        if (wv < 2) GLOAD_LDS(thH_g + goff, &thH[u * 8]);
        else        GLOAD_LDS(thL_g + goff, &thL[u * 8]);
    }

    f32x4 sc[2][16] = {};

    #pragma unroll
    for (int ch = 0; ch < 4; ++ch) {
        __syncthreads();   // prev-chunk ds_reads done -> phB writable
        #pragma unroll
        for (int it = 0; it < 4; ++it) {   // phi chunk: 1024 units x 2 halves
            const int u = it * 256 + tid;
            const int row = u >> 2, j = u & 3;
            const int gj = j ^ ((row >> 1) & 3);
            const size_t goff = ((size_t)b * P_ + ch * 256 + row) * 32 + gj * 8;
            GLOAD_LDS(phH_g + goff, &phH[u * 8]);
            GLOAD_LDS(phL_g + goff, &phL[u * 8]);
        }
        __syncthreads();   // vmcnt(0) drained before barrier -> data visible

        bf16x8 Ah[2], Al[2];
        #pragma unroll
        for (int mf = 0; mf < 2; ++mf) {
            const int tr = mf * 16 + lr;
            const int ja = lk ^ ((tr >> 1) & 3);
            Ah[mf] = *(const bf16x8*)&thH[tr * 32 + ja * 8];
            Al[mf] = *(const bf16x8*)&thL[tr * 32 + ja * 8];
        }
        #pragma unroll
        for (int q = 0; q < 4; ++q) {
            const int pr = wv * 64 + q * 16 + lr;
            const int jb = lk ^ ((pr >> 1) & 3);
            const bf16x8 Bh = *(const bf16x8*)&phH[pr * 32 + jb * 8];
            const bf16x8 Bl = *(const bf16x8*)&phL[pr * 32 + jb * 8];
            #pragma unroll
            for (int mf = 0; mf < 2; ++mf) {
                f32x4 a = sc[mf][ch * 4 + q];
                a = __builtin_amdgcn_mfma_f32_16x16x32_bf16(Ah[mf], Bh, a, 0, 0, 0);
                a = __builtin_amdgcn_mfma_f32_16x16x32_bf16(Ah[mf], Bl, a, 0, 0, 0);
                a = __builtin_amdgcn_mfma_f32_16x16x32_bf16(Al[mf], Bh, a, 0, 0, 0);
                sc[mf][ch * 4 + q] = a;
            }
        }
    }

    // ---- softmax over p; rows t = mf*16 + lk*4 + r ----
    float mrow[2][4];
    #pragma unroll
    for (int mf = 0; mf < 2; ++mf)
        #pragma unroll
        for (int r = 0; r < 4; ++r) {
            float m = sc[mf][0][r];
            #pragma unroll
            for (int qg = 1; qg < 16; ++qg) m = fmaxf(m, sc[mf][qg][r]);
            #pragma unroll
            for (int off = 1; off < 16; off <<= 1) m = fmaxf(m, __shfl_xor(m, off));
            mrow[mf][r] = m;
        }
    if (lr == 0)
        #pragma unroll
        for (int mf = 0; mf < 2; ++mf)
            #pragma unroll
            for (int r = 0; r < 4; ++r)
                red[(mf * 16 + lk * 4 + r) * 4 + wv] = mrow[mf][r];
    __syncthreads();
    #pragma unroll
    for (int mf = 0; mf < 2; ++mf)
        #pragma unroll
        for (int r = 0; r < 4; ++r) {
            const int t = mf * 16 + lk * 4 + r;
            mrow[mf][r] = fmaxf(fmaxf(red[t * 4 + 0], red[t * 4 + 1]),
                                fmaxf(red[t * 4 + 2], red[t * 4 + 3]));
        }
    __syncthreads();   // before red reuse for sums

    float rl[2][4];
    #pragma unroll
    for (int mf = 0; mf < 2; ++mf)
        #pragma unroll
        for (int r = 0; r < 4; ++r) {
            float s = 0.f;
            #pragma unroll
            for (int qg = 0; qg < 16; ++qg) {
                float e = __expf(sc[mf][qg][r] - mrow[mf][r]);
                sc[mf][qg][r] = e; s += e;
            }
            #pragma unroll
            for (int off = 1; off < 16; off <<= 1) s += __shfl_xor(s, off);
            rl[mf][r] = s;
        }
    if (lr == 0)
        #pragma unroll
        for (int mf = 0; mf < 2; ++mf)
            #pragma unroll
            for (int r = 0; r < 4; ++r)
                red[(mf * 16 + lk * 4 + r) * 4 + wv] = rl[mf][r];
    __syncthreads();
    #pragma unroll
    for (int mf = 0; mf < 2; ++mf)
        #pragma unroll
        for (int r = 0; r < 4; ++r) {
            const int t = mf * 16 + lk * 4 + r;
            rl[mf][r] = 1.0f / (red[t * 4 + 0] + red[t * 4 + 1] +
                                red[t * 4 + 2] + red[t * 4 + 3]);
        }

    // ---- beta store: p = (qg>>2)*256 + wv*64 + (qg&3)*16 + lr ----
    unsigned short* bb = beta + ((size_t)b * HW_ + t0) * P_;
    #pragma unroll
    for (int mf = 0; mf < 2; ++mf)
        #pragma unroll
        for (int qg = 0; qg < 16; ++qg) {
            const int p = (qg >> 2) * 256 + wv * 64 + (qg & 3) * 16 + lr;
            #pragma unroll
            for (int r = 0; r < 4; ++r)
                bb[(size_t)(mf * 16 + lk * 4 + r) * P_ + p] = f2bf(sc[mf][qg][r] * rl[mf][r]);
        }
}

// ---------------------------------------------------------------------------
// K4: out = gamma * (W_og @ beta^T) + x, bf16 MFMA.
// Round-3-verified structure + rule-21 XOR swizzle (j ^= row&7): fragment
// reads go 16-way -> 8-way bank conflict (floor for 128B rows).
// ---------------------------------------------------------------------------
__global__ __launch_bounds__(256) void k4_mfma(
    const unsigned short* __restrict__ wog, const unsigned short* __restrict__ beta,
    const float* __restrict__ x, const float* __restrict__ gamma_p,
    float* __restrict__ out)
{
    const int t0 = blockIdx.x * 128, c0 = blockIdx.y * 128, b = blockIdx.z;
    const int tid = threadIdx.x, wv = tid >> 6, lane = tid & 63;
    const int wm = wv >> 1, wn = wv & 1;
    const int lr = lane & 15, lk = lane >> 4;
    __shared__ unsigned short As[128 * 64];
    __shared__ unsigned short Bs[128 * 64];

    f32x4 acc[4][4] = {};
    const unsigned short* wog_b  = wog  + ((size_t)b * C_  + c0) * P_;
    const unsigned short* beta_b = beta + ((size_t)b * HW_ + t0) * P_;

    for (int p0 = 0; p0 < 1024; p0 += 64) {
        __syncthreads();
        #pragma unroll
        for (int ch = 0; ch < 4; ++ch) {
            const int i16 = ch * 256 + tid;
            const int row = i16 >> 3, cb8 = i16 & 7;
            const int gcb = cb8 ^ (row & 7);          // pre-swizzled source
            GLOAD_LDS(wog_b  + (size_t)row * P_ + p0 + gcb * 8, &As[i16 * 8]);
            GLOAD_LDS(beta_b + (size_t)row * P_ + p0 + gcb * 8, &Bs[i16 * 8]);
        }
        __syncthreads();

        #pragma unroll
        for (int ks = 0; ks < 2; ++ks) {
            bf16x8 af[4], bfr[4];
            #pragma unroll
            for (int mf = 0; mf < 4; ++mf) {
                const int arow = wm * 64 + mf * 16 + lr;
                const int ja = (ks * 4 + lk) ^ (arow & 7);
                af[mf] = *(const bf16x8*)&As[arow * 64 + ja * 8];
            }
            #pragma unroll
            for (int nf = 0; nf < 4; ++nf) {
                const int brow = wn * 64 + nf * 16 + lr;
                const int jb = (ks * 4 + lk) ^ (brow & 7);
                bfr[nf] = *(const bf16x8*)&Bs[brow * 64 + jb * 8];
            }
            #pragma unroll
            for (int mf = 0; mf < 4; ++mf)
                #pragma unroll
                for (int nf = 0; nf < 4; ++nf)
                    acc[mf][nf] = __builtin_amdgcn_mfma_f32_16x16x32_bf16(
                        af[mf], bfr[nf], acc[mf][nf], 0, 0, 0);
        }
    }

    const float gm = gamma_p[0];
    #pragma unroll
    for (int mf = 0; mf < 4; ++mf) {
        #pragma unroll
        for (int r = 0; r < 4; ++r) {
            const int co = c0 + wm * 64 + mf * 16 + lk * 4 + r;
            const size_t rowoff = ((size_t)b * C_ + co) * HW_;
            #pragma unroll
            for (int nf = 0; nf < 4; ++nf) {
                const int t = t0 + wn * 64 + nf * 16 + lr;
                out[rowoff + t] = gm * acc[mf][nf][r] + x[rowoff + t];
            }
        }
    }
}

// ---------------------------------------------------------------------------
extern "C" void kernel_launch(void* const* d_in, const int* in_sizes, int n_in,
                              void* d_out, int out_size, void* d_ws, size_t ws_size,
                              hipStream_t stream)
{
    const float* x       = (const float*)d_in[0];
    const float* w_theta = (const float*)d_in[1];
    const float* w_phi   = (const float*)d_in[2];
    const float* w_g     = (const float*)d_in[3];
    const float* w_o     = (const float*)d_in[4];
    const float* gamma   = (const float*)d_in[5];
    float* out = (float*)d_out;
    float* ws  = (float*)d_ws;

    unsigned short* thH  = (unsigned short*)(ws + WS_THH);
    unsigned short* thL  = (unsigned short*)(ws + WS_THL);
    unsigned short* phH  = (unsigned short*)(ws + WS_PHH);
    unsigned short* phL  = (unsigned short*)(ws + WS_PHL);
    float* g             = ws + WS_G;
    unsigned short* wog  = (unsigned short*)(ws + WS_WOG);
    unsigned short* beta = (unsigned short*)(ws + WS_BETA);

    k1_proj<<<dim3(32, 3, 16), 256, 0, stream>>>(x, w_theta, w_phi, w_g,
                                                 thH, thL, phH, phL, g);
    k2_wog<<<dim3(16, 4, 16), 256, 0, stream>>>(w_o, g, wog);
    k3_mfma<<<dim3(128, 16), 256, 0, stream>>>(thH, thL, phH, phL, beta);
    k4_mfma<<<dim3(32, 2, 16), 256, 0, stream>>>(wog, beta, x, gamma, out);
}